// Round 9
// baseline (382.104 us; speedup 1.0000x reference)
//
#include <hip/hip_runtime.h>
#include <math.h>

#define NN 50000
#define EE 800000
#define HH 4
#define CC 64
#define DE 16
#define GG 64
#define HC 256          // H*C
#define NEG 0.2f
#define EPSV 1e-5f
#define NREP 8          // histogram/cursor replicas (~per-XCD)
#define NT8 (NREP * NN)              // 400000 scan elements
#define NB8 ((NT8 + 255) / 256)      // 1563 scan blocks
#define CH2 ((NB8 + 255) / 256)      // 7: scanB chunk

typedef __attribute__((ext_vector_type(8))) short short8;
typedef __attribute__((ext_vector_type(4))) float f32x4;

__device__ __forceinline__ unsigned short f2bf(float f) {
  unsigned int x = __float_as_uint(f);
  unsigned int r = (x + 0x7fff + ((x >> 16) & 1)) >> 16;  // round-nearest-even
  return (unsigned short)r;
}
__device__ __forceinline__ float lrelu(float a) {
  return fmaxf(a, 0.f) + NEG * fminf(a, 0.f);
}

// K0: blocks 0..63: Wb[k][t] = bf16(W[k][colmap(t)]), colmap(t)=(t&3)*64+(t>>2).
//     block 64: v_edge. blocks 65+: zero hist8 (replaces hipMemsetAsync).
__global__ __launch_bounds__(256) void k_prep(
    const float* __restrict__ W, const float* __restrict__ We,
    const float* __restrict__ ae_, unsigned short* __restrict__ Wb,
    float* __restrict__ v_edge, int* __restrict__ hist8) {
  int b = blockIdx.x, t = threadIdx.x;
  if (b < 64) {
    Wb[b * HC + t] = f2bf(W[b * HC + (t & 3) * 64 + (t >> 2)]);
  } else if (b == 64) {
    if (t < DE * HH) {
      int d = t >> 2, h = t & 3;
      float s = 0.f;
      for (int c = 0; c < CC; ++c) s += We[d * HC + h * CC + c] * ae_[h * CC + c];
      v_edge[t] = s;
    }
  } else {
    int idx = (b - 65) * 256 + t;
    if (idx < NT8) hist8[idx] = 0;
  }
}

// K1: MFMA projection + fused a_src/a_dst logits. Verified gfx950 layouts.
__global__ __launch_bounds__(256) void k_xproj(
    const float* __restrict__ node, const unsigned short* __restrict__ Wb,
    const float* __restrict__ att_src, const float* __restrict__ att_dst,
    unsigned short* __restrict__ x16, float* __restrict__ a_src,
    float* __restrict__ a_dst) {
  int lane = threadIdx.x & 63;
  int w = threadIdx.x >> 6;
  int m = lane & 15, quad = lane >> 4;
  int m0 = blockIdx.x * 16;
  const float* arow = node + (size_t)(m0 + m) * CC + quad * 8;
  float4 af0 = *(const float4*)(arow);
  float4 af1 = *(const float4*)(arow + 4);
  float4 af2 = *(const float4*)(arow + 32);
  float4 af3 = *(const float4*)(arow + 36);
  short8 a0 = {(short)f2bf(af0.x), (short)f2bf(af0.y), (short)f2bf(af0.z),
               (short)f2bf(af0.w), (short)f2bf(af1.x), (short)f2bf(af1.y),
               (short)f2bf(af1.z), (short)f2bf(af1.w)};
  short8 a1 = {(short)f2bf(af2.x), (short)f2bf(af2.y), (short)f2bf(af2.z),
               (short)f2bf(af2.w), (short)f2bf(af3.x), (short)f2bf(af3.y),
               (short)f2bf(af3.z), (short)f2bf(af3.w)};
  float sa[4] = {0, 0, 0, 0}, sd[4] = {0, 0, 0, 0};
#pragma unroll
  for (int i = 0; i < 4; ++i) {
    int t = (w * 4 + i) * 16 + m;
    short8 b0, b1;
#pragma unroll
    for (int j = 0; j < 8; ++j) {
      b0[j] = (short)Wb[(quad * 8 + j) * HC + t];
      b1[j] = (short)Wb[(32 + quad * 8 + j) * HC + t];
    }
    f32x4 acc = {0.f, 0.f, 0.f, 0.f};
    acc = __builtin_amdgcn_mfma_f32_16x16x32_bf16(a0, b0, acc, 0, 0, 0);
    acc = __builtin_amdgcn_mfma_f32_16x16x32_bf16(a1, b1, acc, 0, 0, 0);
    float us_t = att_src[(t & 3) * CC + (t >> 2)];
    float ud_t = att_dst[(t & 3) * CC + (t >> 2)];
#pragma unroll
    for (int r = 0; r < 4; ++r) {
      x16[(size_t)(m0 + quad * 4 + r) * HC + t] = f2bf(acc[r]);
      sa[r] += acc[r] * us_t;
      sd[r] += acc[r] * ud_t;
    }
  }
  __shared__ float lss[4][16][4], lsd[4][16][4];
#pragma unroll
  for (int r = 0; r < 4; ++r) {
    sa[r] += __shfl_xor(sa[r], 4);
    sa[r] += __shfl_xor(sa[r], 8);
    sd[r] += __shfl_xor(sd[r], 4);
    sd[r] += __shfl_xor(sd[r], 8);
  }
  if ((lane & 12) == 0) {
#pragma unroll
    for (int r = 0; r < 4; ++r) {
      lss[w][quad * 4 + r][lane & 3] = sa[r];
      lsd[w][quad * 4 + r][lane & 3] = sd[r];
    }
  }
  __syncthreads();
  int t = threadIdx.x;
  if (t < 64) {
    int row = t >> 2, h = t & 3;
    a_src[(size_t)(m0 + row) * 4 + h] =
        lss[0][row][h] + lss[1][row][h] + lss[2][row][h] + lss[3][row][h];
    a_dst[(size_t)(m0 + row) * 4 + h] =
        lsd[0][row][h] + lsd[1][row][h] + lsd[2][row][h] + lsd[3][row][h];
  }
}

// K2: dst histogram, 8-way replicated by block (replica ~ XCD) to cut
// same-line atomic ping-pong. Replica choice must match k_edge_perm.
__global__ __launch_bounds__(256) void k_hist(
    const int* __restrict__ ei, int* __restrict__ hist8) {
  int e = blockIdx.x * 256 + threadIdx.x;
  if (e >= EE) return;
  int rep = blockIdx.x & (NREP - 1);
  atomicAdd(&hist8[rep * NN + ei[EE + e]], 1);
}

// K3a: per-block sums over the (n,r)-ordered virtual array of hist8.
__global__ __launch_bounds__(256) void k_scanA(
    const int* __restrict__ hist8, int* __restrict__ bsum) {
  __shared__ int s[256];
  int t = threadIdx.x;
  int idx = blockIdx.x * 256 + t;
  int v = 0;
  if (idx < NT8) v = hist8[(idx & (NREP - 1)) * NN + (idx >> 3)];
  s[t] = v;
  __syncthreads();
  for (int d = 128; d; d >>= 1) {
    if (t < d) s[t] += s[t + d];
    __syncthreads();
  }
  if (t == 0) bsum[blockIdx.x] = s[0];
}

// K3b: single block: exclusive scan of NB8 block sums (CH2 per thread).
__global__ __launch_bounds__(256) void k_scanB(
    const int* __restrict__ bsum, int* __restrict__ boff,
    int* __restrict__ ptr) {
  __shared__ int s[256];
  int t = threadIdx.x;
  int base = t * CH2;
  int v = 0;
  for (int i = 0; i < CH2; ++i) {
    int idx = base + i;
    if (idx < NB8) v += bsum[idx];
  }
  s[t] = v;
  __syncthreads();
  for (int d = 1; d < 256; d <<= 1) {
    int u = (t >= d) ? s[t - d] : 0;
    __syncthreads();
    s[t] += u;
    __syncthreads();
  }
  int run = (t == 0) ? 0 : s[t - 1];
  for (int i = 0; i < CH2; ++i) {
    int idx = base + i;
    if (idx < NB8) {
      boff[idx] = run;
      run += bsum[idx];
    }
  }
  if (t == 255) ptr[NN] = s[255];
}

// K3c: per-block exclusive scan + boff -> cursor8 (per dst,replica offsets);
// r==0 entry also gives ptr[n].
__global__ __launch_bounds__(256) void k_scanC(
    const int* __restrict__ hist8, const int* __restrict__ boff,
    int* __restrict__ ptr, int* __restrict__ cursor8) {
  __shared__ int s[256];
  int t = threadIdx.x;
  int idx = blockIdx.x * 256 + t;
  int n = idx >> 3, r = idx & (NREP - 1);
  int v = 0;
  if (idx < NT8) v = hist8[r * NN + n];
  s[t] = v;
  __syncthreads();
  for (int d = 1; d < 256; d <<= 1) {
    int u = (t >= d) ? s[t - d] : 0;
    __syncthreads();
    s[t] += u;
    __syncthreads();
  }
  if (idx < NT8) {
    int p = boff[blockIdx.x] + s[t] - v;
    cursor8[r * NN + n] = p;
    if (r == 0) ptr[n] = p;
  }
}

// K4: fused edge pass: t = exp(lrelu(a_src[sn]+a_dst[dn]+edge_attr@v)), then
// scatter ONE packed uint4 {bf16 t0..t3, sn, e} via the replicated cursor.
__global__ __launch_bounds__(256) void k_edge_perm(
    const float* __restrict__ edge_attr, const int* __restrict__ ei,
    const float* __restrict__ a_src, const float* __restrict__ a_dst,
    const float* __restrict__ v_edge, int* __restrict__ cursor8,
    uint4* __restrict__ recs) {
  __shared__ float vs[DE * HH];
  int t = threadIdx.x;
  if (t < DE * HH) vs[t] = v_edge[t];
  __syncthreads();
  int e = blockIdx.x * 256 + t;
  if (e >= EE) return;
  const float4* ea4 = (const float4*)(edge_attr + (size_t)e * DE);
  float ae[4] = {0, 0, 0, 0};
#pragma unroll
  for (int dd = 0; dd < 4; ++dd) {
    float4 ev = ea4[dd];
    float evs[4] = {ev.x, ev.y, ev.z, ev.w};
#pragma unroll
    for (int j = 0; j < 4; ++j) {
      int d = dd * 4 + j;
#pragma unroll
      for (int h = 0; h < 4; ++h) ae[h] += evs[j] * vs[d * 4 + h];
    }
  }
  int sn = ei[e], dn = ei[EE + e];
  float4 as4 = *(const float4*)(a_src + (size_t)sn * 4);
  float4 ad4 = *(const float4*)(a_dst + (size_t)dn * 4);
  float t0 = __expf(lrelu(as4.x + ad4.x + ae[0]));
  float t1 = __expf(lrelu(as4.y + ad4.y + ae[1]));
  float t2 = __expf(lrelu(as4.z + ad4.z + ae[2]));
  float t3 = __expf(lrelu(as4.w + ad4.w + ae[3]));
  uint4 rec;
  rec.x = (unsigned int)f2bf(t0) | ((unsigned int)f2bf(t1) << 16);
  rec.y = (unsigned int)f2bf(t2) | ((unsigned int)f2bf(t3) << 16);
  rec.z = (unsigned int)sn;
  rec.w = (unsigned int)e;
  int rep = blockIdx.x & (NREP - 1);
  int pos = atomicAdd(&cursor8[rep * NN + dn], 1);
  recs[pos] = rec;
}

// K5: one wave per dst node; unroll 4 for memory-level parallelism.
__global__ __launch_bounds__(256) void k_gat(
    const int* __restrict__ ptr, const uint4* __restrict__ recs,
    const unsigned short* __restrict__ x16, float* __restrict__ out_acc,
    float* __restrict__ att_out) {
  int lane = threadIdx.x & 63;
  int w = threadIdx.x >> 6;
  int v = blockIdx.x * 4 + w;
  int start = ptr[v], end = ptr[v + 1];
  float d0 = 0.f, d1 = 0.f, d2 = 0.f, d3 = 0.f;
  float acc0 = 0.f, acc1 = 0.f, acc2 = 0.f, acc3 = 0.f;
#pragma unroll 4
  for (int j = start; j < end; ++j) {
    uint4 rec = recs[j];                       // wave-uniform broadcast
    float t0 = __uint_as_float(rec.x << 16);
    float t1 = __uint_as_float(rec.x & 0xffff0000u);
    float t2 = __uint_as_float(rec.y << 16);
    float t3 = __uint_as_float(rec.y & 0xffff0000u);
    uint2 u = *(const uint2*)(x16 + (size_t)rec.z * HC + lane * 4);
    d0 += t0; d1 += t1; d2 += t2; d3 += t3;
    acc0 += t0 * __uint_as_float(u.x << 16);
    acc1 += t1 * __uint_as_float(u.x & 0xffff0000u);
    acc2 += t2 * __uint_as_float(u.y << 16);
    acc3 += t3 * __uint_as_float(u.y & 0xffff0000u);
  }
  float r0 = 1.f / (d0 + 1e-16f), r1 = 1.f / (d1 + 1e-16f);
  float r2 = 1.f / (d2 + 1e-16f), r3 = 1.f / (d3 + 1e-16f);
  out_acc[(size_t)v * CC + lane] =
      0.25f * (r0 * acc0 + r1 * acc1 + r2 * acc2 + r3 * acc3);
  for (int j = start + lane; j < end; j += 64) {
    uint4 rec = recs[j];
    float t0 = __uint_as_float(rec.x << 16) * r0;
    float t1 = __uint_as_float(rec.x & 0xffff0000u) * r1;
    float t2 = __uint_as_float(rec.y << 16) * r2;
    float t3 = __uint_as_float(rec.y & 0xffff0000u) * r3;
    *(float4*)(att_out + (size_t)rec.w * 4) = make_float4(t0, t1, t2, t3);
  }
}

// K6: fused GraphNorm stats + normalize + affine + relu. One block per group;
// group rows are L2-resident between the stats pass and the write pass.
__global__ __launch_bounds__(256) void k_statsfinal(
    const int* __restrict__ batch, const float* __restrict__ out_acc,
    const float* __restrict__ bias, const float* __restrict__ gns,
    const float* __restrict__ gnw, const float* __restrict__ gnb,
    float* __restrict__ y) {
  int g = blockIdx.x;
  int lane = threadIdx.x & 63;
  int w = threadIdx.x >> 6;
  int lo = 0, hi = NN;
  while (lo < hi) {
    int mid = (lo + hi) >> 1;
    if (batch[mid] < g) lo = mid + 1; else hi = mid;
  }
  int start = lo;
  hi = NN;
  while (lo < hi) {
    int mid = (lo + hi) >> 1;
    if (batch[mid] < g + 1) lo = mid + 1; else hi = mid;
  }
  int end = lo;
  float b = bias[lane];
  float s1 = 0.f, s2 = 0.f;
  for (int n = start + w; n < end; n += 4) {
    float v = out_acc[(size_t)n * CC + lane] + b;
    s1 += v;
    s2 += v * v;
  }
  __shared__ float l1[4][64], l2[4][64];
  __shared__ float ms_l[64], is_l[64];
  l1[w][lane] = s1;
  l2[w][lane] = s2;
  __syncthreads();
  if (w == 0) {
    s1 = l1[0][lane] + l1[1][lane] + l1[2][lane] + l1[3][lane];
    s2 = l2[0][lane] + l2[1][lane] + l2[2][lane] + l2[3][lane];
    float c = fmaxf((float)(end - start), 1.0f);
    float mean = s1 / c;
    float ms = mean * gns[lane];
    float var = s2 / c - 2.f * ms * mean + ms * ms;
    ms_l[lane] = ms;
    is_l[lane] = rsqrtf(var + EPSV);
  }
  __syncthreads();
  float ms = ms_l[lane], isd = is_l[lane];
  float gw = gnw[lane], gb = gnb[lane];
  for (int n = start + w; n < end; n += 4) {
    float v = out_acc[(size_t)n * CC + lane] + b;
    float o = (v - ms) * isd;
    y[(size_t)n * CC + lane] = fmaxf(gw * o + gb, 0.0f);
  }
}

extern "C" void kernel_launch(void* const* d_in, const int* in_sizes, int n_in,
                              void* d_out, int out_size, void* d_ws, size_t ws_size,
                              hipStream_t stream) {
  const float* node = (const float*)d_in[0];
  const int* ei = (const int*)d_in[1];
  const float* eatt = (const float*)d_in[2];
  const int* batch = (const int*)d_in[3];
  const float* W = (const float*)d_in[4];
  const float* We = (const float*)d_in[5];
  const float* att_src = (const float*)d_in[6];
  const float* att_dst = (const float*)d_in[7];
  const float* att_edge = (const float*)d_in[8];
  const float* bias = (const float*)d_in[9];
  const float* gnw = (const float*)d_in[10];
  const float* gnb = (const float*)d_in[11];
  const float* gns = (const float*)d_in[12];

  float* ws = (float*)d_ws;
  size_t off = 0;
  uint4* recs = (uint4*)(ws + off);  off += (size_t)EE * 4;  // 12.8 MB
  float* a_src = ws + off;    off += (size_t)NN * HH;
  float* a_dst = ws + off;    off += (size_t)NN * HH;
  float* v_edge = ws + off;   off += 64;
  float* out_acc = ws + off;  off += (size_t)NN * CC;
  unsigned short* x16 = (unsigned short*)(ws + off);
  off += (size_t)NN * HC / 2;                           // 12.8M ushort
  unsigned short* Wb = (unsigned short*)(ws + off);
  off += (size_t)CC * HC / 2;
  int* iws = (int*)(ws + off);
  size_t ioff = 0;
  int* hist8 = iws + ioff;    ioff += NT8;
  int* cursor8 = iws + ioff;  ioff += NT8;
  int* ptr = iws + ioff;      ioff += NN + 1;
  int* bsum = iws + ioff;     ioff += NB8;
  int* boff = iws + ioff;     ioff += NB8;

  float* y_out = (float*)d_out;
  float* att_out = (float*)d_out + (size_t)NN * CC;

  k_prep<<<65 + NB8, 256, 0, stream>>>(W, We, att_edge, Wb, v_edge, hist8);
  k_hist<<<(EE + 255) / 256, 256, 0, stream>>>(ei, hist8);
  k_xproj<<<NN / 16, 256, 0, stream>>>(node, Wb, att_src, att_dst, x16, a_src,
                                       a_dst);
  k_scanA<<<NB8, 256, 0, stream>>>(hist8, bsum);
  k_scanB<<<1, 256, 0, stream>>>(bsum, boff, ptr);
  k_scanC<<<NB8, 256, 0, stream>>>(hist8, boff, ptr, cursor8);
  k_edge_perm<<<(EE + 255) / 256, 256, 0, stream>>>(eatt, ei, a_src, a_dst,
                                                    v_edge, cursor8, recs);
  k_gat<<<NN / 4, 256, 0, stream>>>(ptr, recs, x16, out_acc, att_out);
  k_statsfinal<<<GG, 256, 0, stream>>>(batch, out_acc, bias, gns, gnw, gnb,
                                       y_out);
}